// Round 3
// baseline (40.142 us; speedup 1.0000x reference)
//
#include <hip/hip_runtime.h>
#include <hip/hip_bf16.h>

#define N_TOT 2048
#define M_DIM 64
#define O_DIM 128
#define NT 8   // neurons per block

typedef __bf16 bf16x8 __attribute__((ext_vector_type(8)));
typedef __bf16 bf16x4 __attribute__((ext_vector_type(4)));
typedef float f32x4 __attribute__((ext_vector_type(4)));

// Grid 256 x 1024 threads (16 waves). Wave w -> neuron (w&7), b-half (w>>3).
// Single full-K stage of w1 (staged ONCE per block), one barrier, then
// per-o-tile MFMA + immediate nontemporal store. 128 KiB LDS -> 1 block/CU,
// 16 waves/CU issuing the gather concurrently.
__global__ __launch_bounds__(1024, 4) void superlinear_mfma(
    const float* __restrict__ x, const float* __restrict__ w1,
    const float* __restrict__ b1, float* __restrict__ out)
{
    // bf16 W tile, logical [nn][o][k64] (k innermost), XOR-swizzled. 128 KiB.
    __shared__ unsigned char wlds[NT * O_DIM * M_DIM * 2];

    const int tid  = threadIdx.x;
    const int lane = tid & 63;
    const int wave = tid >> 6;   // 0..15

    // XCD-aware swizzle: 256 blocks / 8 XCDs -> 32 consecutive nblk per XCD
    const int bid  = blockIdx.x;
    const int nblk = (bid & 7) * 32 + (bid >> 3);
    const int n0   = nblk * NT;

    const int nn  = wave & 7;    // neuron owned by this wave
    const int bh  = wave >> 3;   // b-half (rows bh*32..+31)
    const int n   = n0 + nn;
    const int col = lane & 15;   // o (and b-row) index within 16-tile
    const int kg  = lane >> 4;   // k-group (8 bf16 each)

    // ---- Issue x loads (A operand) early; convert later during stage-wait ----
    float4 xr[2][2][2];
    #pragma unroll
    for (int kc = 0; kc < 2; ++kc) {
        #pragma unroll
        for (int bt = 0; bt < 2; ++bt) {
            int b = bh * 32 + bt * 16 + col;
            const float* xp = x + ((size_t)b * N_TOT + n) * M_DIM + kc * 32 + kg * 8;
            xr[kc][bt][0] = *(const float4*)xp;
            xr[kc][bt][1] = *(const float4*)(xp + 4);
        }
    }
    // bias (per-o), issued early
    float bv[8];
    #pragma unroll
    for (int ot = 0; ot < 8; ++ot)
        bv[ot] = b1[(size_t)n * O_DIM + ot * 16 + col];

    // ---- Stage w1[:, :, n0:n0+8] -> LDS bf16 [nn][o][k], swizzled ----
    // unit u = 16 elements: 4 m x 4 n at fixed o; 4096 units = 4 it x 1024 thr.
    // Per thread: 16 float4 loads, issuable deep.
    #pragma unroll
    for (int it = 0; it < 4; ++it) {
        int u  = it * 1024 + tid;
        int n4 = u & 1;
        int o  = (u >> 1) & 127;
        int mq = u >> 8;            // 0..15
        int m  = mq * 4;
        const float* gp = w1 + ((size_t)m * O_DIM + o) * N_TOT + n0 + n4 * 4;
        float4 r0 = *(const float4*)(gp);
        float4 r1 = *(const float4*)(gp + (size_t)O_DIM * N_TOT);
        float4 r2 = *(const float4*)(gp + (size_t)2 * O_DIM * N_TOT);
        float4 r3 = *(const float4*)(gp + (size_t)3 * O_DIM * N_TOT);
        const float* a0 = (const float*)&r0;
        const float* a1 = (const float*)&r1;
        const float* a2 = (const float*)&r2;
        const float* a3 = (const float*)&r3;
        #pragma unroll
        for (int j = 0; j < 4; ++j) {
            int nnw = n4 * 4 + j;
            bf16x4 pk;
            pk[0] = (__bf16)a0[j];
            pk[1] = (__bf16)a1[j];
            pk[2] = (__bf16)a2[j];
            pk[3] = (__bf16)a3[j];
            unsigned addr = (unsigned)(nnw * 16384 + o * 128 + m * 2);
            addr ^= (unsigned)((o & 7) << 4);   // bank swizzle bits 4-6
            *(bf16x4*)(wlds + addr) = pk;
        }
    }

    // ---- Convert x fragments while stage-writes drain ----
    bf16x8 af[2][2];
    #pragma unroll
    for (int kc = 0; kc < 2; ++kc) {
        #pragma unroll
        for (int bt = 0; bt < 2; ++bt) {
            const float* lp = (const float*)&xr[kc][bt][0];
            const float* hp = (const float*)&xr[kc][bt][1];
            bf16x8 v;
            #pragma unroll
            for (int j = 0; j < 4; ++j) {
                v[j]     = (__bf16)lp[j];
                v[4 + j] = (__bf16)hp[j];
            }
            af[kc][bt] = v;
        }
    }

    __syncthreads();

    // ---- Per o-tile: 2 LDS b128 reads, 4 MFMAs, 8 nontemporal stores ----
    #pragma unroll
    for (int ot = 0; ot < 8; ++ot) {
        unsigned addr = (unsigned)(nn * 16384 + (ot * 16 + col) * 128 + kg * 16);
        addr ^= (unsigned)((col & 7) << 4);
        bf16x8 bf0 = *(const bf16x8*)(wlds + addr);          // kc = 0
        bf16x8 bf1 = *(const bf16x8*)(wlds + (addr ^ 64u));  // kc = 1 (bit6 = kc)
        f32x4 ci;
        ci[0] = bv[ot]; ci[1] = bv[ot]; ci[2] = bv[ot]; ci[3] = bv[ot];
        #pragma unroll
        for (int bt = 0; bt < 2; ++bt) {
            f32x4 a = __builtin_amdgcn_mfma_f32_16x16x32_bf16(af[0][bt], bf0, ci, 0, 0, 0);
            a       = __builtin_amdgcn_mfma_f32_16x16x32_bf16(af[1][bt], bf1, a,  0, 0, 0);
            #pragma unroll
            for (int r = 0; r < 4; ++r) {
                int b = bh * 32 + bt * 16 + kg * 4 + r;
                __builtin_nontemporal_store(
                    a[r], out + ((size_t)b * N_TOT + n) * O_DIM + ot * 16 + col);
            }
        }
    }
}

extern "C" void kernel_launch(void* const* d_in, const int* in_sizes, int n_in,
                              void* d_out, int out_size, void* d_ws, size_t ws_size,
                              hipStream_t stream) {
    const float* x  = (const float*)d_in[0];
    const float* w1 = (const float*)d_in[1];
    const float* b1 = (const float*)d_in[2];
    float* out = (float*)d_out;
    superlinear_mfma<<<dim3(256), dim3(1024), 0, stream>>>(x, w1, b1, out);
}

// Round 4
// 38.207 us; speedup vs baseline: 1.0507x; 1.0507x over previous
//
#include <hip/hip_runtime.h>
#include <hip/hip_bf16.h>

#define N_TOT 2048
#define M_DIM 64
#define O_DIM 128
#define NT 4   // neurons per block

typedef __bf16 bf16x8 __attribute__((ext_vector_type(8)));
typedef __bf16 bf16x4 __attribute__((ext_vector_type(4)));
typedef float f32x4 __attribute__((ext_vector_type(4)));

// Grid 512 x 512 threads (8 waves). Block owns 4 neurons (full K, full B):
// LDS 64 KiB -> 2 blocks/CU resident, so one block's compute/store overlaps
// the other's w1 gather. Wave w -> neuron (w&3), b-half (w>>2).
__global__ __launch_bounds__(512, 4) void superlinear_mfma(
    const float* __restrict__ x, const float* __restrict__ w1,
    const float* __restrict__ b1, float* __restrict__ out)
{
    // bf16 W tile, logical [nn][o][k64] (k innermost), XOR-swizzled. 64 KiB.
    __shared__ unsigned char wlds[NT * O_DIM * M_DIM * 2];

    const int tid  = threadIdx.x;
    const int lane = tid & 63;
    const int wave = tid >> 6;   // 0..7

    // XCD-aware swizzle (512 % 8 == 0 -> bijective). 64 consecutive nblk per
    // XCD => the 4 nblks sharing each w1 cache line hit the same L2.
    const int bid  = blockIdx.x;
    const int nblk = (bid & 7) * 64 + (bid >> 3);
    const int n0   = nblk * NT;

    const int nn  = wave & 3;    // neuron owned by this wave
    const int bh  = wave >> 2;   // b-half (rows bh*32..+31)
    const int n   = n0 + nn;
    const int col = lane & 15;   // o (and b-row) index within 16-tile
    const int kg  = lane >> 4;   // k-group (8 bf16 each)

    // ---- Issue x loads (A operand) early; convert during stage-wait ----
    float4 xr[2][2][2];
    #pragma unroll
    for (int kc = 0; kc < 2; ++kc) {
        #pragma unroll
        for (int bt = 0; bt < 2; ++bt) {
            int b = bh * 32 + bt * 16 + col;
            const float* xp = x + ((size_t)b * N_TOT + n) * M_DIM + kc * 32 + kg * 8;
            xr[kc][bt][0] = *(const float4*)xp;
            xr[kc][bt][1] = *(const float4*)(xp + 4);
        }
    }
    // bias (per-o), issued early
    float bv[8];
    #pragma unroll
    for (int ot = 0; ot < 8; ++ot)
        bv[ot] = b1[(size_t)n * O_DIM + ot * 16 + col];

    // ---- Stage w1[:, :, n0:n0+4] -> LDS bf16 [nn][o][k], swizzled ----
    // unit u: 4 m-rows x float4(4 n) at fixed o; 2048 units = 4 it x 512 thr.
    // Consecutive lanes -> consecutive o.
    #pragma unroll
    for (int it = 0; it < 4; ++it) {
        int u  = it * 512 + tid;
        int o  = u & 127;
        int mq = u >> 7;            // 0..15
        int m  = mq * 4;
        const float* gp = w1 + ((size_t)m * O_DIM + o) * N_TOT + n0;
        float4 r0 = *(const float4*)(gp);
        float4 r1 = *(const float4*)(gp + (size_t)O_DIM * N_TOT);
        float4 r2 = *(const float4*)(gp + (size_t)2 * O_DIM * N_TOT);
        float4 r3 = *(const float4*)(gp + (size_t)3 * O_DIM * N_TOT);
        const float* a0 = (const float*)&r0;
        const float* a1 = (const float*)&r1;
        const float* a2 = (const float*)&r2;
        const float* a3 = (const float*)&r3;
        #pragma unroll
        for (int j = 0; j < 4; ++j) {      // j = neuron index within block
            bf16x4 pk;
            pk[0] = (__bf16)a0[j];
            pk[1] = (__bf16)a1[j];
            pk[2] = (__bf16)a2[j];
            pk[3] = (__bf16)a3[j];
            unsigned addr = (unsigned)(j * 16384 + o * 128 + m * 2);
            addr ^= (unsigned)((o & 7) << 4);   // bank swizzle bits 4-6
            *(bf16x4*)(wlds + addr) = pk;
        }
    }

    // ---- Convert x fragments while stage-writes drain ----
    bf16x8 af[2][2];
    #pragma unroll
    for (int kc = 0; kc < 2; ++kc) {
        #pragma unroll
        for (int bt = 0; bt < 2; ++bt) {
            const float* lp = (const float*)&xr[kc][bt][0];
            const float* hp = (const float*)&xr[kc][bt][1];
            bf16x8 v;
            #pragma unroll
            for (int j = 0; j < 4; ++j) {
                v[j]     = (__bf16)lp[j];
                v[4 + j] = (__bf16)hp[j];
            }
            af[kc][bt] = v;
        }
    }

    __syncthreads();

    // ---- Per o-tile: 2 LDS b128 reads, 4 MFMAs, 8 plain stores ----
    #pragma unroll
    for (int ot = 0; ot < 8; ++ot) {
        unsigned addr = (unsigned)(nn * 16384 + (ot * 16 + col) * 128 + kg * 16);
        addr ^= (unsigned)((col & 7) << 4);
        bf16x8 bf0 = *(const bf16x8*)(wlds + addr);          // kc = 0
        bf16x8 bf1 = *(const bf16x8*)(wlds + (addr ^ 64u));  // kc = 1 (bit6 = kc)
        f32x4 ci;
        ci[0] = bv[ot]; ci[1] = bv[ot]; ci[2] = bv[ot]; ci[3] = bv[ot];
        #pragma unroll
        for (int bt = 0; bt < 2; ++bt) {
            f32x4 a = __builtin_amdgcn_mfma_f32_16x16x32_bf16(af[0][bt], bf0, ci, 0, 0, 0);
            a       = __builtin_amdgcn_mfma_f32_16x16x32_bf16(af[1][bt], bf1, a,  0, 0, 0);
            #pragma unroll
            for (int r = 0; r < 4; ++r) {
                int b = bh * 32 + bt * 16 + kg * 4 + r;
                out[((size_t)b * N_TOT + n) * O_DIM + ot * 16 + col] = a[r];
            }
        }
    }
}

extern "C" void kernel_launch(void* const* d_in, const int* in_sizes, int n_in,
                              void* d_out, int out_size, void* d_ws, size_t ws_size,
                              hipStream_t stream) {
    const float* x  = (const float*)d_in[0];
    const float* w1 = (const float*)d_in[1];
    const float* b1 = (const float*)d_in[2];
    float* out = (float*)d_out;
    superlinear_mfma<<<dim3(512), dim3(512), 0, stream>>>(x, w1, b1, out);
}

// Round 5
// 35.697 us; speedup vs baseline: 1.1245x; 1.0703x over previous
//
#include <hip/hip_runtime.h>
#include <hip/hip_bf16.h>

#define N_TOT 2048
#define M_DIM 64
#define O_DIM 128
#define NT 8   // neurons per block

typedef __bf16 bf16x8 __attribute__((ext_vector_type(8)));
typedef __bf16 bf16x4 __attribute__((ext_vector_type(4)));
typedef float f32x4 __attribute__((ext_vector_type(4)));

// Grid 256 x 512 threads (1 block/CU, wave w -> neuron n0+w, full 64 b-rows).
// W is staged in 8 chunks of 16 o-columns (16 KiB each, double-buffered):
// per chunk: issue next-chunk loads -> MFMA current -> ds_write next ->
// store current -> lgkmcnt(0) + raw s_barrier. Reads and writes interleave
// for the whole kernel (no bunched read-then-write phases).
__global__ __launch_bounds__(512, 2) void superlinear_mfma(
    const float* __restrict__ x, const float* __restrict__ w1,
    const float* __restrict__ b1, float* __restrict__ out)
{
    __shared__ unsigned char wlds[2 * NT * 16 * M_DIM * 2];  // 2 x 16 KiB

    const int tid  = threadIdx.x;
    const int lane = tid & 63;
    const int wave = tid >> 6;   // 0..7 = neuron within block

    // XCD-aware swizzle: 256 blocks / 8 XCDs -> 32 consecutive nblk per XCD
    const int bid  = blockIdx.x;
    const int nblk = (bid & 7) * 32 + (bid >> 3);
    const int n0   = nblk * NT;
    const int n    = n0 + wave;

    const int col = lane & 15;   // o (and b-row) index within 16-tile
    const int kg  = lane >> 4;   // k-group (8 bf16)

    // staging decomposition: thread -> (half of 32B n-extent, o-local, 4 m rows)
    const int half = tid & 1;
    const int ol   = (tid >> 1) & 15;
    const int m4   = (tid >> 5) * 4;

    const size_t MSTR = (size_t)O_DIM * N_TOT;   // w1 m-stride (floats)

    auto stage_issue = [&](int ot, float4* r) {
        const float* gp = w1 + (size_t)m4 * MSTR + (size_t)(ot * 16 + ol) * N_TOT
                             + n0 + half * 4;
        r[0] = *(const float4*)gp;
        r[1] = *(const float4*)(gp + MSTR);
        r[2] = *(const float4*)(gp + 2 * MSTR);
        r[3] = *(const float4*)(gp + 3 * MSTR);
    };
    auto stage_write = [&](int ot, const float4* r) {
        unsigned base = (unsigned)(ot & 1) << 14;
        const float* a0 = (const float*)&r[0];
        const float* a1 = (const float*)&r[1];
        const float* a2 = (const float*)&r[2];
        const float* a3 = (const float*)&r[3];
        #pragma unroll
        for (int j = 0; j < 4; ++j) {        // j -> neuron nn = half*4+j
            int nn = half * 4 + j;
            bf16x4 pk;
            pk[0] = (__bf16)a0[j];
            pk[1] = (__bf16)a1[j];
            pk[2] = (__bf16)a2[j];
            pk[3] = (__bf16)a3[j];
            unsigned addr = (unsigned)(nn * 2048 + ol * 128 + m4 * 2);
            addr ^= (unsigned)((ol & 7) << 4);   // bank swizzle bits 4-6
            *(bf16x4*)(wlds + base + addr) = pk;
        }
    };

    // ---- Prologue: chunk-0 W loads first (oldest in vm queue) ----
    float4 sr[4];
    stage_issue(0, sr);

    // bias for all 8 o-tiles
    float bv[8];
    #pragma unroll
    for (int ot = 0; ot < 8; ++ot)
        bv[ot] = b1[(size_t)n * O_DIM + ot * 16 + col];

    // x fragments (A operand), full B column for this wave's neuron
    float4 xr[2][4][2];
    #pragma unroll
    for (int kc = 0; kc < 2; ++kc)
        #pragma unroll
        for (int bt = 0; bt < 4; ++bt) {
            int b = bt * 16 + col;
            const float* xp = x + ((size_t)b * N_TOT + n) * M_DIM + kc * 32 + kg * 8;
            xr[kc][bt][0] = *(const float4*)xp;
            xr[kc][bt][1] = *(const float4*)(xp + 4);
        }

    // write chunk 0 (waits only the 4 oldest loads), then convert x
    stage_write(0, sr);

    bf16x8 af[2][4];
    #pragma unroll
    for (int kc = 0; kc < 2; ++kc)
        #pragma unroll
        for (int bt = 0; bt < 4; ++bt) {
            const float* lp = (const float*)&xr[kc][bt][0];
            const float* hp = (const float*)&xr[kc][bt][1];
            bf16x8 v;
            #pragma unroll
            for (int j = 0; j < 4; ++j) {
                v[j]     = (__bf16)lp[j];
                v[4 + j] = (__bf16)hp[j];
            }
            af[kc][bt] = v;
        }

    asm volatile("s_waitcnt lgkmcnt(0)" ::: "memory");
    __builtin_amdgcn_s_barrier();
    __builtin_amdgcn_sched_barrier(0);

    // ---- Main loop over 8 o-chunks ----
    #pragma unroll
    for (int ot = 0; ot < 8; ++ot) {
        float4 srn[4];
        if (ot < 7) stage_issue(ot + 1, srn);   // next chunk into flight

        // current chunk: 2 LDS b128 reads + 8 MFMAs
        unsigned base = (unsigned)(ot & 1) << 14;
        unsigned addr = (unsigned)(wave * 2048 + col * 128 + kg * 16);
        addr ^= (unsigned)((col & 7) << 4);
        bf16x8 bf0 = *(const bf16x8*)(wlds + base + addr);          // k 0..31
        bf16x8 bf1 = *(const bf16x8*)(wlds + base + (addr ^ 64u));  // k 32..63

        f32x4 a[4];
        #pragma unroll
        for (int bt = 0; bt < 4; ++bt) {
            f32x4 ci;
            ci[0] = bv[ot]; ci[1] = bv[ot]; ci[2] = bv[ot]; ci[3] = bv[ot];
            a[bt] = __builtin_amdgcn_mfma_f32_16x16x32_bf16(af[0][bt], bf0, ci,    0, 0, 0);
            a[bt] = __builtin_amdgcn_mfma_f32_16x16x32_bf16(af[1][bt], bf1, a[bt], 0, 0, 0);
        }

        // convert + ds_write next chunk (vmcnt wait lands here, covered by MFMA)
        if (ot < 7) stage_write(ot + 1, srn);

        // store current chunk (issued after the last vmcnt wait of this iter,
        // so store-acks get a full iteration to retire before the next wait)
        #pragma unroll
        for (int bt = 0; bt < 4; ++bt)
            #pragma unroll
            for (int r = 0; r < 4; ++r) {
                int b = bt * 16 + kg * 4 + r;
                out[((size_t)b * N_TOT + n) * O_DIM + ot * 16 + col] = a[bt][r];
            }

        if (ot < 7) {
            // raw barrier: LDS visibility only (lgkm), never drain the stores
            asm volatile("s_waitcnt lgkmcnt(0)" ::: "memory");
            __builtin_amdgcn_s_barrier();
            __builtin_amdgcn_sched_barrier(0);
        }
    }
}

extern "C" void kernel_launch(void* const* d_in, const int* in_sizes, int n_in,
                              void* d_out, int out_size, void* d_ws, size_t ws_size,
                              hipStream_t stream) {
    const float* x  = (const float*)d_in[0];
    const float* w1 = (const float*)d_in[1];
    const float* b1 = (const float*)d_in[2];
    float* out = (float*)d_out;
    superlinear_mfma<<<dim3(256), dim3(512), 0, stream>>>(x, w1, b1, out);
}

// Round 7
// 35.407 us; speedup vs baseline: 1.1337x; 1.0082x over previous
//
#include <hip/hip_runtime.h>
#include <hip/hip_bf16.h>

#define N_TOT 2048
#define M_DIM 64
#define O_DIM 128
#define NT 8   // neurons per block

typedef __bf16 bf16x8 __attribute__((ext_vector_type(8)));
typedef float f32x4 __attribute__((ext_vector_type(4)));

// Grid 256 x 512 thr (1 block/CU, wave w = neuron n0+w, full 64 b-rows).
// W staged in 4 chunks of 32 o-columns (32 KiB), TRIPLE-buffered: the
// ds_write of chunk c+1 waits on global loads issued one full iteration
// earlier (latency covered), while chunk c+2's loads go into flight.
// Stores emit each (b,n)-row's full 128 B o-pair back-to-back (clean HBM
// write-back). Barriers are lgkm-only (stores never drained).
// r6 bugfix: swizzle applied LAST on reads (r6 added +64 to an already-
// swizzled address; carry out of bit 6 read wrong/OOB LDS -> NaN).
__global__ __launch_bounds__(512, 2) void superlinear_mfma(
    const float* __restrict__ x, const float* __restrict__ w1,
    const float* __restrict__ b1, float* __restrict__ out)
{
    __shared__ unsigned char wlds[3 * NT * 32 * M_DIM * 2];  // 3 x 32 KiB

    const int tid  = threadIdx.x;
    const int lane = tid & 63;
    const int wave = tid >> 6;   // 0..7 = neuron within block (compute role)

    // XCD-aware swizzle: 256 blocks / 8 XCDs -> 32 consecutive nblk per XCD
    const int bid  = blockIdx.x;
    const int nblk = (bid & 7) * 32 + (bid >> 3);
    const int n0   = nblk * NT;
    const int n    = n0 + wave;

    const int col = lane & 15;   // o (and b-row) index within 16-tile
    const int kg  = lane >> 4;   // k-group (8 bf16)

    // staging decomposition: thread -> (n-half, o-local in chunk, 8 m-rows)
    const int half = tid & 1;
    const int ol   = (tid >> 1) & 31;
    const int mseg = tid >> 6;            // m-rows mseg*8 .. +7

    const size_t MSTR = (size_t)O_DIM * N_TOT;   // w1 m-stride (floats)

    auto stage_issue = [&](int c, float4* r) {
        const float* gp = w1 + ((size_t)(mseg * 8) * O_DIM + (c * 32 + ol)) * N_TOT
                             + n0 + half * 4;
        #pragma unroll
        for (int mm = 0; mm < 8; ++mm)
            r[mm] = *(const float4*)(gp + (size_t)mm * MSTR);
    };
    // LDS layout per buffer: [nn][ol 0..31][k 0..63] bf16, addr ^= (ol&7)<<4.
    // Thread holds 8 k-consecutive values per neuron -> one ds_write_b128 each.
    auto stage_write = [&](int c, const float4* r) {
        unsigned base = (unsigned)(c % 3) * 32768u;
        #pragma unroll
        for (int j = 0; j < 4; ++j) {
            int nn = half * 4 + j;
            bf16x8 v;
            #pragma unroll
            for (int mm = 0; mm < 8; ++mm)
                v[mm] = (__bf16)(((const float*)&r[mm])[j]);
            unsigned addr = (unsigned)(nn * 4096 + ol * 128 + mseg * 16);
            addr ^= (unsigned)((ol & 7) << 4);
            *(bf16x8*)(wlds + base + addr) = v;
        }
    };

    // ---- Prologue ----
    float4 srA[8], srB[8];
    stage_issue(0, srA);                 // oldest in vm queue -> drains first

    // x fragments (A operand): full 64 b-rows for this wave's neuron
    float4 xr[2][4][2];
    #pragma unroll
    for (int kc = 0; kc < 2; ++kc)
        #pragma unroll
        for (int bt = 0; bt < 4; ++bt) {
            int b = bt * 16 + col;
            const float* xp = x + ((size_t)b * N_TOT + n) * M_DIM + kc * 32 + kg * 8;
            xr[kc][bt][0] = *(const float4*)xp;
            xr[kc][bt][1] = *(const float4*)(xp + 4);
        }
    float bv[8];
    #pragma unroll
    for (int ot = 0; ot < 8; ++ot)
        bv[ot] = b1[(size_t)n * O_DIM + ot * 16 + col];

    stage_issue(1, srB);                 // chunk 1 into flight behind x

    stage_write(0, srA);                 // waits only chunk-0 loads

    bf16x8 af[2][4];                     // convert x while writes drain
    #pragma unroll
    for (int kc = 0; kc < 2; ++kc)
        #pragma unroll
        for (int bt = 0; bt < 4; ++bt) {
            const float* lp = (const float*)&xr[kc][bt][0];
            const float* hp = (const float*)&xr[kc][bt][1];
            bf16x8 v;
            #pragma unroll
            for (int j = 0; j < 4; ++j) {
                v[j]     = (__bf16)lp[j];
                v[4 + j] = (__bf16)hp[j];
            }
            af[kc][bt] = v;
        }

    asm volatile("s_waitcnt lgkmcnt(0)" ::: "memory");
    __builtin_amdgcn_s_barrier();
    __builtin_amdgcn_sched_barrier(0);

    // ---- Main loop: 4 chunks of 32 o-columns ----
    const unsigned sw = (unsigned)(col & 7) << 4;
    #pragma unroll
    for (int c = 0; c < 4; ++c) {
        if (c < 2) stage_issue(c + 2, (c & 1) ? srB : srA);  // 1 iter ahead +1

        // compute chunk c: 4 ds_read_b128 + 16 MFMAs
        unsigned base = (unsigned)(c % 3) * 32768u;
        f32x4 acc[4][2];
        #pragma unroll
        for (int otl = 0; otl < 2; ++otl) {
            // logical addr first (bit 6 clean: kg*16 <= 48), swizzle LAST
            unsigned la = (unsigned)(wave * 4096 + otl * 2048 + col * 128 + kg * 16);
            bf16x8 bf0 = *(const bf16x8*)(wlds + base + (la ^ sw));         // k 0..31
            bf16x8 bf1 = *(const bf16x8*)(wlds + base + ((la + 64) ^ sw));  // k 32..63
            f32x4 ci;
            float b0 = bv[c * 2 + otl];
            ci[0] = b0; ci[1] = b0; ci[2] = b0; ci[3] = b0;
            #pragma unroll
            for (int bt = 0; bt < 4; ++bt) {
                acc[bt][otl] = __builtin_amdgcn_mfma_f32_16x16x32_bf16(af[0][bt], bf0, ci,           0, 0, 0);
                acc[bt][otl] = __builtin_amdgcn_mfma_f32_16x16x32_bf16(af[1][bt], bf1, acc[bt][otl], 0, 0, 0);
            }
        }

        // ds_write chunk c+1 (its loads were issued one full iteration ago)
        if (c < 3) stage_write(c + 1, (c & 1) ? srA : srB);

        // store chunk c: both 64 B halves of each (b,n)-row's 128 B region
        // back-to-back -> clean write-back
        #pragma unroll
        for (int bt = 0; bt < 4; ++bt)
            #pragma unroll
            for (int r = 0; r < 4; ++r) {
                int b = bt * 16 + kg * 4 + r;
                float* op = out + ((size_t)b * N_TOT + n) * O_DIM + c * 32 + col;
                op[0]  = acc[bt][0][r];
                op[16] = acc[bt][1][r];
            }

        if (c < 3) {
            asm volatile("s_waitcnt lgkmcnt(0)" ::: "memory");
            __builtin_amdgcn_s_barrier();
            __builtin_amdgcn_sched_barrier(0);
        }
    }
}

extern "C" void kernel_launch(void* const* d_in, const int* in_sizes, int n_in,
                              void* d_out, int out_size, void* d_ws, size_t ws_size,
                              hipStream_t stream) {
    const float* x  = (const float*)d_in[0];
    const float* w1 = (const float*)d_in[1];
    const float* b1 = (const float*)d_in[2];
    float* out = (float*)d_out;
    superlinear_mfma<<<dim3(256), dim3(512), 0, stream>>>(x, w1, b1, out);
}